// Round 5
// baseline (362.961 us; speedup 1.0000x reference)
//
#include <hip/hip_runtime.h>

// Problem constants (fixed shape)
// N=8192 tokens, D=1280, H=16 heads, K=80 head dim (pad 96), S=16 segs, L=512
#define LOG2E 1.44269504088896340736f
#define ATT_SCALE 0.11180339887498949f  // 80^-0.5

typedef _Float16 half8 __attribute__((ext_vector_type(8)));
typedef _Float16 half4v __attribute__((ext_vector_type(4)));
typedef __fp16 fp16x2 __attribute__((ext_vector_type(2)));
typedef float f32x4 __attribute__((ext_vector_type(4)));

#define MFMA(a, b, c) __builtin_amdgcn_mfma_f32_16x16x32_f16((a), (b), (c), 0, 0, 0)

__device__ __forceinline__ void async16(const _Float16* g, _Float16* l) {
  __builtin_amdgcn_global_load_lds(
      (const __attribute__((address_space(1))) unsigned int*)g,
      (__attribute__((address_space(3))) unsigned int*)l,
      16, 0, 0);
}

#define FENCE() asm volatile("" ::: "memory")
// one barrier per phase, memory fence only (no sched pins — m141)
#define PHB()                                   \
  do {                                          \
    FENCE();                                    \
    __builtin_amdgcn_s_barrier();               \
    FENCE();                                    \
  } while (0)

// ---------------- fp32 -> fp16 convert (hidden) ----------------
__global__ __launch_bounds__(256) void cvt_k(const float* __restrict__ in,
                                             _Float16* __restrict__ out, int n4) {
  int i = blockIdx.x * 256 + threadIdx.x;
  if (i < n4) {
    f32x4 v = ((const f32x4*)in)[i];
    half4v hv;
    hv[0] = (_Float16)v[0]; hv[1] = (_Float16)v[1];
    hv[2] = (_Float16)v[2]; hv[3] = (_Float16)v[3];
    ((half4v*)out)[i] = hv;
  }
}

// ---------------- transpose + convert: in R x C fp32 -> out C x R fp16 ----------
__global__ __launch_bounds__(256) void transpose_cvt_k(const float* __restrict__ in,
                                                       _Float16* __restrict__ out,
                                                       int R, int C) {
  __shared__ float tile[32][33];
  const int tx = threadIdx.x & 31, ty = threadIdx.x >> 5;
  const int c0 = blockIdx.x * 32, r0 = blockIdx.y * 32;
#pragma unroll
  for (int i = 0; i < 32; i += 8)
    tile[ty + i][tx] = in[(size_t)(r0 + ty + i) * C + c0 + tx];
  __syncthreads();
#pragma unroll
  for (int i = 0; i < 32; i += 8)
    out[(size_t)(c0 + ty + i) * R + r0 + tx] = (_Float16)tile[tx][ty + i];
}

// ---------------- GEMM0: 256x128 tile, BK=32, 4-wave block, 2 blocks/CU -------
// C = A(8192x1280) * BT^T (3840x1280), scatter epilogue -> Qf/Kf/VTf
//
// Round-5 theory: every prior variant had acc[8][4]=128 AGPR + ~124 VGPR =
// ~252 combined regs (gfx950 unified file) -> 2 waves/SIMD, and all 8 waves
// of the single resident block shared ONE barrier group: during its
// read/barrier window the whole CU's matrix pipe idled (MfmaUtil stuck at
// 28-29% across R0/R2/R4 schedules). Fix: 4-wave blocks (256 thr), tile
// 256x128, BK=32, LDS 48 KB -> TWO independent blocks/CU. Each SIMD hosts
// one wave from each block; block A's barrier stall is filled by block B's
// MFMA (m114 mechanism). Per-wave geometry stays 128x64 (keeps LDS
// bytes/FLOP low; per-CU window: matrix ~1240 cyc vs LDS ~1125 cyc).
//
// Per tile t (40 tiles of BK=32; buf = t&1):
//   q0: BAR; read afA(r0-half, 4) + bf(4); stage A(t+1)->buf^1; MFMA i0-3 (16)
//   q1: BAR; read afA(r1-half, 4);         stage B(t+2)->buf;  vmcnt; MFMA i4-7
// vmcnt(2) once per tile (q1): drains A(t+1)+B(t+1), leaves B(t+2)x2 in
// flight — counted, never 0 mid-loop (T4). A's prefetch lead is 1 phase:
// safe ONLY because A is XCD-L2-pinned (hit ~200 cyc). Hazards audited:
// each stage-write is barrier-separated from the last read of its region
// (reads drain before each reader's own MFMA -> before its barrier arrival).
//
// XCD mapping (kept): XCD x owns tm in [4x,4x+4), sweeps tn in 0..29 ->
// A working set 2.6 MB/XCD, L2-pinned, 30x reuse. id = tn*32 + q*8 + xcd.
// Swizzle (rule #21, 64 B rows): LDS dest linear; source pre-permuted
// lg = g ^ (row&3); reads use pg = quad ^ (l16&3) (same involution).
// Balanced 8 accesses per 16B slot-class -> conflict-free b128.
__global__ __launch_bounds__(256, 2) void gemm256_k(const _Float16* __restrict__ A,
                                                    const _Float16* __restrict__ BT,
                                                    const float* __restrict__ bias,
                                                    _Float16* __restrict__ Qf,
                                                    _Float16* __restrict__ Kf,
                                                    _Float16* __restrict__ VTf) {
  __shared__ _Float16 sA[2][256 * 32];  // 16 KB per buf
  __shared__ _Float16 sB[2][128 * 32];  //  8 KB per buf   (total 48 KB)
  const int tid = threadIdx.x;
  const int wave = tid >> 6, lane = tid & 63;
  const int quad = lane >> 4, l16 = lane & 15;
  const int wm = wave >> 1, wn = wave & 1;  // wave grid 2M x 2N, per-wave 128x64
  const int KD = 1280, NT = 40;             // 40 K-tiles of 32

  // A-pinned XCD mapping: 960 blocks = 8 xcd * 4 q * 30 tn
  const int id = blockIdx.x;
  const int xcd = id & 7;
  const int qq = (id >> 3) & 3;
  const int tn = id >> 5;           // 0..29
  const int tm = xcd * 4 + qq;      // 0..31
  const int m0 = tm * 256, n0 = tn * 128;

  f32x4 acc[8][4] = {};

  // stage full A tile (256x32 = 16 KB, 4 DMA rounds) / B tile (128x32, 2 rounds)
  // slot s = c*256 + tid; row = s>>2; source group pre-swizzled lg = (s&3)^(row&3)
  auto stageA = [&](int buf, int kt) {
#pragma unroll
    for (int c = 0; c < 4; ++c) {
      const int s = c * 256 + tid;
      const int row = s >> 2;
      const int lg = (s & 3) ^ (row & 3);
      async16(A + (size_t)(m0 + row) * KD + kt * 32 + lg * 8,
              &sA[buf][(size_t)(c * 256 + wave * 64) * 8]);
    }
  };
  auto stageB = [&](int buf, int kt) {
#pragma unroll
    for (int c = 0; c < 2; ++c) {
      const int s = c * 256 + tid;
      const int row = s >> 2;
      const int lg = (s & 3) ^ (row & 3);
      async16(BT + (size_t)(n0 + row) * KD + kt * 32 + lg * 8,
              &sB[buf][(size_t)(c * 256 + wave * 64) * 8]);
    }
  };
  // A fragments: 4 row-frags from row-half rh of this wave's 128-row half
  auto ldA = [&](half8* af, const _Float16* base, int rh) {
#pragma unroll
    for (int i = 0; i < 4; ++i) {
      const int row = wm * 128 + rh * 64 + i * 16 + l16;
      const int pg = quad ^ (l16 & 3);   // row&3 == l16&3 here
      af[i] = *(const half8*)(base + row * 32 + pg * 8);
    }
  };
  // B fragments: 4 col-frags from this wave's 64-row half of B
  auto ldB = [&](half8* bf, const _Float16* base) {
#pragma unroll
    for (int j = 0; j < 4; ++j) {
      const int row = wn * 64 + j * 16 + l16;
      const int pg = quad ^ (l16 & 3);
      bf[j] = *(const half8*)(base + row * 32 + pg * 8);
    }
  };
  // one 16-MFMA half: rows rh*64..+63 x all 64 cols
  auto mmaq = [&](int rh, const half8* af, const half8* bf) {
#pragma unroll
    for (int i = 0; i < 4; ++i)
#pragma unroll
      for (int j = 0; j < 4; ++j)
        acc[rh * 4 + i][j] = MFMA(af[i], bf[j], acc[rh * 4 + i][j]);
  };

  // prologue: A(0), B(0), B(1); vmcnt(2) drains tile0, leaves B(1)x2 in flight
  stageA(0, 0);
  stageB(0, 0);
  stageB(1, 1);
  asm volatile("s_waitcnt vmcnt(2)" ::: "memory");

  half8 af[4], bf[4];
#pragma unroll 2
  for (int t = 0; t < NT; ++t) {
    const int buf = t & 1;
    const _Float16* aB = &sA[buf][0];
    const _Float16* bB = &sB[buf][0];

    // ---- q0: MFMA rows 0-63; stage A(t+1)
    PHB();
    ldA(af, aB, 0);
    ldB(bf, bB);
    if (t + 1 < NT) stageA(buf ^ 1, t + 1);
    __builtin_amdgcn_s_setprio(1);
    mmaq(0, af, bf);
    __builtin_amdgcn_s_setprio(0);

    // ---- q1: MFMA rows 64-127; stage B(t+2); counted vmcnt checkpoint
    PHB();
    ldA(af, aB, 1);
    if (t + 2 < NT) stageB(buf, t + 2);
    if (t == NT - 2)
      asm volatile("s_waitcnt vmcnt(0)" ::: "memory");  // final drain
    else if (t < NT - 2)
      asm volatile("s_waitcnt vmcnt(2)" ::: "memory");  // counted, never 0
    __builtin_amdgcn_s_setprio(1);
    mmaq(1, af, bf);
    __builtin_amdgcn_s_setprio(0);
  }

  // scatter epilogue: C row = quad*4+reg, col = l16 within fragment [m89-verified]
#pragma unroll
  for (int ridx = 0; ridx < 8; ++ridx) {
#pragma unroll
    for (int cidx = 0; cidx < 4; ++cidx) {
      const int col = n0 + wn * 64 + cidx * 16 + l16;
      const float bv = bias[col];
      const int rowb = m0 + wm * 128 + ridx * 16 + quad * 4;
      const int which = col / 1280;
      const int rem = col - which * 1280;
      const int h = rem / 80;
      const int kk = rem - h * 80;
#pragma unroll
      for (int r = 0; r < 4; ++r) {
        const float v = acc[ridx][cidx][r] + bv;
        const int mrow = rowb + r;
        const int s = mrow >> 9, l = mrow & 511;
        const int shh = s * 16 + h;
        if (which == 0)
          Qf[((size_t)shh * 512 + l) * 96 + kk] = (_Float16)v;
        else if (which == 1)
          Kf[((size_t)shh * 512 + l) * 96 + kk] = (_Float16)v;
        else
          VTf[((size_t)shh * 80 + kk) * 512 + l] = (_Float16)v;
      }
    }
  }
}

// ---------------- GEMM1: 128x128 tile (proj): Out fp32 = A * projT^T + bias --
__global__ __launch_bounds__(256) void gemm_k(const _Float16* __restrict__ A,
                                              const _Float16* __restrict__ BT,
                                              const float* __restrict__ bias,
                                              float* __restrict__ Out) {
  __shared__ _Float16 sA[128 * 32];
  __shared__ _Float16 sB[128 * 32];
  const int tid = threadIdx.x;
  const int wave = tid >> 6, lane = tid & 63;
  const int quad = lane >> 4, l16 = lane & 15;
  const int m0 = blockIdx.x * 128;
  const int n0 = blockIdx.y * 128;
  const int mw = (wave & 1) * 64, nw = (wave >> 1) * 64;
  const int KD = 1280;

  const int srcg = (lane & 3) ^ ((lane >> 3) & 3);
  const int rg = (quad ^ ((l16 >> 1) & 3)) * 8;

  f32x4 acc[4][4] = {};

  for (int kt = 0; kt < KD; kt += 32) {
#pragma unroll
    for (int c = 0; c < 2; ++c) {
      const int j = wave * 2 + c;
      const int row = j * 16 + (lane >> 2);
      async16(A + (size_t)(m0 + row) * KD + kt + srcg * 8, &sA[j * 512]);
      async16(BT + (size_t)(n0 + row) * KD + kt + srcg * 8, &sB[j * 512]);
    }
    __syncthreads();
    half8 af[4], bf[4];
#pragma unroll
    for (int i = 0; i < 4; ++i) {
      af[i] = *(const half8*)&sA[(mw + i * 16 + l16) * 32 + rg];
      bf[i] = *(const half8*)&sB[(nw + i * 16 + l16) * 32 + rg];
    }
#pragma unroll
    for (int i = 0; i < 4; ++i)
#pragma unroll
      for (int j2 = 0; j2 < 4; ++j2)
        acc[i][j2] = MFMA(af[i], bf[j2], acc[i][j2]);
    __syncthreads();
  }

#pragma unroll
  for (int i = 0; i < 4; ++i) {
#pragma unroll
    for (int j2 = 0; j2 < 4; ++j2) {
      const int col = n0 + nw + j2 * 16 + l16;
      const float bv = bias[col];
      const int rowb = m0 + mw + i * 16 + quad * 4;
#pragma unroll
      for (int r = 0; r < 4; ++r)
        Out[(size_t)(rowb + r) * 1280 + col] = acc[i][j2][r] + bv;
    }
  }
}

// ---------------- RoPE in-place on Qf/Kf + zero the k-pad [80,96) -------------
__global__ __launch_bounds__(256) void rope_k(_Float16* __restrict__ Qf,
                                              _Float16* __restrict__ Kf,
                                              const float* __restrict__ cosNK,
                                              const float* __restrict__ sinNK) {
  const int gid = blockIdx.x * 256 + threadIdx.x;
  const int j = gid & 63;
  const int row = gid >> 6;
  const int qk = row >> 17;
  const int r = row & 131071;      // (s*16+h)*512 + l
  _Float16* buf = qk ? Kf : Qf;
  const int l = r & 511;
  const int s = r >> 13;
  const int t = s * 512 + l;
  const size_t base = (size_t)r * 96;
  if (j < 40) {
    const float v1 = (float)buf[base + j];
    const float v2 = (float)buf[base + j + 40];
    const float c1 = cosNK[t * 80 + j], s1 = sinNK[t * 80 + j];
    const float c2 = cosNK[t * 80 + j + 40], s2 = sinNK[t * 80 + j + 40];
    buf[base + j] = (_Float16)(v1 * c1 - v2 * s1);
    buf[base + j + 40] = (_Float16)(v2 * c2 + v1 * s2);
  } else if (j < 56) {
    buf[base + 40 + j] = (_Float16)0.f;  // kk = 80..95
  }
}

// ---------------- flash attention (S^T form, no-max softmax, sum via ones) ----
__global__ __launch_bounds__(256) void attn_k(const _Float16* __restrict__ Qf,
                                              const _Float16* __restrict__ Kf,
                                              const _Float16* __restrict__ VTf,
                                              _Float16* __restrict__ attnA) {
  __shared__ _Float16 sP[128 * 72];   // P tile, row stride 72
  __shared__ _Float16 sK[64 * 104];   // K tile, row stride 104 (conflict-free)
  __shared__ _Float16 sV[96 * 72];    // rows 0..79: V^T tile; rows 80..95: ones
  const int tid = threadIdx.x;
  const int wave = tid >> 6, lane = tid & 63;
  const int quad = lane >> 4, l16 = lane & 15;
  const int shh = blockIdx.x;  // s*16+h
  const int qt = blockIdx.y;   // 0..3
  const int h = shh & 15;
  const int s = shh >> 4;

  const _Float16* Qb = Qf + ((size_t)shh * 512 + qt * 128) * 96;
  const _Float16* Kb0 = Kf + (size_t)shh * 512 * 96;
  const _Float16* Vb0 = VTf + (size_t)shh * 80 * 512;

  // Q fragments straight from global (rows are lane-exact), pre-scaled
  const _Float16 c1h = (_Float16)(ATT_SCALE * LOG2E);
  half8 qf[2][3];
#pragma unroll
  for (int rt = 0; rt < 2; ++rt)
#pragma unroll
    for (int ks = 0; ks < 3; ++ks) {
      half8 t = *(const half8*)(Qb + (size_t)(wave * 32 + rt * 16 + l16) * 96 +
                                ks * 32 + quad * 8);
#pragma unroll
      for (int e = 0; e < 8; ++e) t[e] *= c1h;
      qf[rt][ks] = t;
    }

  // ones rows for the row-sum trick
  for (int idx = tid; idx < 16 * 72; idx += 256) sV[80 * 72 + idx] = (_Float16)1.f;

  f32x4 o[2][6] = {};  // ft 0..4: output features; ft 5: row sum

  for (int kc = 0; kc < 8; ++kc) {
    __syncthreads();  // prev iter LDS reads done (iter0: ones visible)
    // K tile -> sK, padded stride 104 halves (208 B), masked DMA (13 chunks)
    const _Float16* Kb = Kb0 + (size_t)kc * 64 * 96;
#pragma unroll
    for (int c = 0; c < 4; ++c) {
      const int j = wave + 4 * c;
      if (j < 13) {
        const int off = j * 1024 + lane * 16;  // LDS byte offset
        const int krow = off / 208;
        const int kcol = off - krow * 208;     // bytes within padded row
        if (kcol < 192)
          async16(Kb + (size_t)krow * 96 + (kcol >> 1), &sK[j * 512]);
      }
    }
    // V^T tile -> sV, padded stride 72 halves (144 B), masked DMA (12 chunks)
#pragma unroll
    for (int c = 0; c < 3; ++c) {
      const int j = wave + 4 * c;
      const int off = j * 1024 + lane * 16;
      const int vrow = off / 144;
      const int colb = off - vrow * 144;
      if (vrow < 80 && colb < 128)
        async16(Vb0 + (size_t)vrow * 512 + kc * 64 + (colb >> 1), &sV[j * 512]);
    }
    __syncthreads();

    // S^T = K Q^T (operand swap): lane holds S[q=l16][k=mt*16+quad*4+r]
    f32x4 sacc[2][4] = {};  // [rt][mt]
#pragma unroll
    for (int mt = 0; mt < 4; ++mt) {
#pragma unroll
      for (int ks = 0; ks < 3; ++ks) {
        half8 kb = *(const half8*)&sK[(mt * 16 + l16) * 104 + ks * 32 + quad * 8];
        sacc[0][mt] = MFMA(kb, qf[0][ks], sacc[0][mt]);
        sacc[1][mt] = MFMA(kb, qf[1][ks], sacc[1][mt]);
      }
    }

    // p = exp2(s), packed pairs (consecutive k!), one b64 store per (rt,mt)
#pragma unroll
    for (int rt = 0; rt < 2; ++rt) {
#pragma unroll
      for (int mt = 0; mt < 4; ++mt) {
        union { fp16x2 h2[2]; half4v h4; } u;
        u.h2[0] = __builtin_amdgcn_cvt_pkrtz(
            __builtin_amdgcn_exp2f(sacc[rt][mt][0]),
            __builtin_amdgcn_exp2f(sacc[rt][mt][1]));
        u.h2[1] = __builtin_amdgcn_cvt_pkrtz(
            __builtin_amdgcn_exp2f(sacc[rt][mt][2]),
            __builtin_amdgcn_exp2f(sacc[rt][mt][3]));
        *(half4v*)&sP[(wave * 32 + rt * 16 + l16) * 72 + mt * 16 + quad * 4] = u.h4;
      }
    }
    // sP rows are wave-private: per-wave LDS ordering suffices, no barrier

    // O += P V  (ft=5 accumulates the row sum via the ones rows)
#pragma unroll
    for (int ks = 0; ks < 2; ++ks) {
      half8 pa[2];
      pa[0] = *(const half8*)&sP[(wave * 32 + 0 + l16) * 72 + ks * 32 + quad * 8];
      pa[1] = *(const half8*)&sP[(wave * 32 + 16 + l16) * 72 + ks * 32 + quad * 8];
#pragma unroll
      for (int ft = 0; ft < 6; ++ft) {
        half8 vb = *(const half8*)&sV[(ft * 16 + l16) * 72 + ks * 32 + quad * 8];
        o[0][ft] = MFMA(pa[0], vb, o[0][ft]);
        o[1][ft] = MFMA(pa[1], vb, o[1][ft]);
      }
    }
  }

  // epilogue: divide by row sum, store fp16 into attnA [token][h*80+f]
#pragma unroll
  for (int rt = 0; rt < 2; ++rt) {
#pragma unroll
    for (int r = 0; r < 4; ++r) {
      const float inv = 1.0f / o[rt][5][r];
      const int token = s * 512 + qt * 128 + wave * 32 + rt * 16 + quad * 4 + r;
#pragma unroll
      for (int ft = 0; ft < 5; ++ft)
        attnA[(size_t)token * 1280 + h * 80 + ft * 16 + l16] =
            (_Float16)(o[rt][ft][r] * inv);
    }
  }
}

extern "C" void kernel_launch(void* const* d_in, const int* in_sizes, int n_in,
                              void* d_out, int out_size, void* d_ws, size_t ws_size,
                              hipStream_t stream) {
  (void)in_sizes; (void)n_in; (void)out_size; (void)ws_size;
  const float* hidden = (const float*)d_in[0];
  const float* cosNK = (const float*)d_in[2];
  const float* sinNK = (const float*)d_in[3];
  const float* qkv_w = (const float*)d_in[4];
  const float* qkv_b = (const float*)d_in[5];
  const float* proj_w = (const float*)d_in[6];
  const float* proj_b = (const float*)d_in[7];
  float* out = (float*)d_out;

  char* ws = (char*)d_ws;
  _Float16* hA    = (_Float16*)(ws);                   // 8192x1280        20971520 B
  _Float16* wT    = (_Float16*)(ws + 20971520);        // 3840x1280         9830400 B
  _Float16* projT = (_Float16*)(ws + 30801920);        // 1280x1280         3276800 B
  _Float16* Qf    = (_Float16*)(ws + 34078720);        // 256x512x96       25165824 B
  _Float16* Kf    = (_Float16*)(ws + 59244544);        // 256x512x96       25165824 B
  _Float16* VTf   = (_Float16*)(ws + 84410368);        // 256x80x512       20971520 B
  _Float16* attnA = (_Float16*)(ws + 105381888);       // 8192x1280        20971520 B

  cvt_k<<<10240, 256, 0, stream>>>(hidden, hA, 2621440);
  transpose_cvt_k<<<dim3(120, 40), 256, 0, stream>>>(qkv_w, wT, 1280, 3840);
  transpose_cvt_k<<<dim3(40, 40), 256, 0, stream>>>(proj_w, projT, 1280, 1280);
  gemm256_k<<<960, 256, 0, stream>>>(hA, wT, qkv_b, Qf, Kf, VTf);
  rope_k<<<65536, 256, 0, stream>>>(Qf, Kf, cosNK, sinNK);
  attn_k<<<dim3(256, 4), 256, 0, stream>>>(Qf, Kf, VTf, attnA);
  gemm_k<<<dim3(64, 10), 256, 0, stream>>>(attnA, projT, proj_b, out);
}

// Round 6
// 358.785 us; speedup vs baseline: 1.0116x; 1.0116x over previous
//
#include <hip/hip_runtime.h>

// Problem constants (fixed shape)
// N=8192 tokens, D=1280, H=16 heads, K=80 head dim (pad 96), S=16 segs, L=512
#define LOG2E 1.44269504088896340736f
#define ATT_SCALE 0.11180339887498949f  // 80^-0.5

typedef _Float16 half8 __attribute__((ext_vector_type(8)));
typedef _Float16 half4v __attribute__((ext_vector_type(4)));
typedef __fp16 fp16x2 __attribute__((ext_vector_type(2)));
typedef float f32x4 __attribute__((ext_vector_type(4)));

#define MFMA(a, b, c) __builtin_amdgcn_mfma_f32_16x16x32_f16((a), (b), (c), 0, 0, 0)

__device__ __forceinline__ void async16(const _Float16* g, _Float16* l) {
  __builtin_amdgcn_global_load_lds(
      (const __attribute__((address_space(1))) unsigned int*)g,
      (__attribute__((address_space(3))) unsigned int*)l,
      16, 0, 0);
}

#define FENCE() asm volatile("" ::: "memory")
// one barrier per phase, memory fence only (no sched pins — m141)
#define PHB()                                   \
  do {                                          \
    FENCE();                                    \
    __builtin_amdgcn_s_barrier();               \
    FENCE();                                    \
  } while (0)

// ---------------- fp32 -> fp16 convert (hidden) ----------------
__global__ __launch_bounds__(256) void cvt_k(const float* __restrict__ in,
                                             _Float16* __restrict__ out, int n4) {
  int i = blockIdx.x * 256 + threadIdx.x;
  if (i < n4) {
    f32x4 v = ((const f32x4*)in)[i];
    half4v hv;
    hv[0] = (_Float16)v[0]; hv[1] = (_Float16)v[1];
    hv[2] = (_Float16)v[2]; hv[3] = (_Float16)v[3];
    ((half4v*)out)[i] = hv;
  }
}

// ---------------- transpose + convert: in R x C fp32 -> out C x R fp16 ----------
__global__ __launch_bounds__(256) void transpose_cvt_k(const float* __restrict__ in,
                                                       _Float16* __restrict__ out,
                                                       int R, int C) {
  __shared__ float tile[32][33];
  const int tx = threadIdx.x & 31, ty = threadIdx.x >> 5;
  const int c0 = blockIdx.x * 32, r0 = blockIdx.y * 32;
#pragma unroll
  for (int i = 0; i < 32; i += 8)
    tile[ty + i][tx] = in[(size_t)(r0 + ty + i) * C + c0 + tx];
  __syncthreads();
#pragma unroll
  for (int i = 0; i < 32; i += 8)
    out[(size_t)(c0 + ty + i) * R + r0 + tx] = (_Float16)tile[tx][ty + i];
}

// ---------------- GEMM0: 256x256 tile, BK=64, 4-phase K-loop (R4, proven) ----
// C = A(8192x1280) * BT^T (3840x1280), scatter epilogue -> Qf/Kf/VTf
// R4 verbatim: 115 us, MfmaUtil 29%, conflicts 0, FETCH 59 MB (ideal).
// R5's BK=32 variant regressed (4-way read conflicts: pg determined by l16&3
// alone within a 16-lane group) and its 2-blocks/CU thesis was falsified
// (register cap -> same 8 waves/CU either way). Reverted.
__global__ __launch_bounds__(512, 2) void gemm256_k(const _Float16* __restrict__ A,
                                                    const _Float16* __restrict__ BT,
                                                    const float* __restrict__ bias,
                                                    _Float16* __restrict__ Qf,
                                                    _Float16* __restrict__ Kf,
                                                    _Float16* __restrict__ VTf) {
  __shared__ _Float16 sA[2][2][128 * 64];  // [buf][half][row*64 + col], 64 KB
  __shared__ _Float16 sB[2][2][128 * 64];  // 64 KB
  const int tid = threadIdx.x;
  const int wave = tid >> 6, lane = tid & 63;
  const int quad = lane >> 4, l16 = lane & 15;
  const int wm = wave >> 2, wn = wave & 3;      // wave grid 2M x 4N
  const int bh = wn >> 1, brb = (wn & 1) * 64;  // B half + row base within half
  const int KD = 1280, NT = 20;                 // 20 K-tiles of 64

  // A-pinned XCD mapping: XCD x owns tm in [4x,4x+4), sweeps tn
  const int id = blockIdx.x;
  const int xcd = id & 7;
  const int qq = (id >> 3) & 3;
  const int tn = id >> 5;           // 0..14
  const int tm = xcd * 4 + qq;      // 0..31
  const int m0 = tm * 256, n0 = tn * 256;

  f32x4 acc[8][4] = {};

  auto stageA = [&](int buf, int half, int kt) {
#pragma unroll
    for (int c = 0; c < 2; ++c) {
      const int s = c * 512 + wave * 64 + lane;
      const int row = s >> 3;
      const int lg = (s & 7) ^ (row & 7);
      async16(A + (size_t)(m0 + half * 128 + row) * KD + kt * 64 + lg * 8,
              &sA[buf][half][(size_t)(c * 512 + wave * 64) * 8]);
    }
  };
  auto stageB = [&](int buf, int half, int kt) {
#pragma unroll
    for (int c = 0; c < 2; ++c) {
      const int s = c * 512 + wave * 64 + lane;
      const int row = s >> 3;
      const int lg = (s & 7) ^ (row & 7);
      async16(BT + (size_t)(n0 + half * 128 + row) * KD + kt * 64 + lg * 8,
              &sB[buf][half][(size_t)(c * 512 + wave * 64) * 8]);
    }
  };
  auto ldA = [&](half8* af, const _Float16* hp, int rh) {
#pragma unroll
    for (int i = 0; i < 4; ++i)
#pragma unroll
      for (int kk = 0; kk < 2; ++kk) {
        const int lrow = rh * 64 + i * 16 + l16;
        const int pg = (kk * 4 + quad) ^ (l16 & 7);
        af[i * 2 + kk] = *(const half8*)(hp + lrow * 64 + pg * 8);
      }
  };
  auto ldB = [&](half8* bf, const _Float16* hp, int ch) {
#pragma unroll
    for (int j = 0; j < 2; ++j)
#pragma unroll
      for (int kk = 0; kk < 2; ++kk) {
        const int brow = brb + ch * 32 + j * 16 + l16;
        const int pg = (kk * 4 + quad) ^ (l16 & 7);
        bf[j * 2 + kk] = *(const half8*)(hp + brow * 64 + pg * 8);
      }
  };
  auto mmaq = [&](int r, int c, const half8* af, const half8* bf) {
#pragma unroll
    for (int i = 0; i < 4; ++i)
#pragma unroll
      for (int j = 0; j < 2; ++j)
#pragma unroll
        for (int kk = 0; kk < 2; ++kk)
          acc[r * 4 + i][c * 2 + j] =
              MFMA(af[i * 2 + kk], bf[j * 2 + kk], acc[r * 4 + i][c * 2 + j]);
  };

  stageA(0, 0, 0); stageA(0, 1, 0);
  stageB(0, 0, 0); stageB(0, 1, 0);
  stageB(1, 0, 1); stageB(1, 1, 1);
  asm volatile("s_waitcnt vmcnt(4)" ::: "memory");

  half8 af[8], bf0[4], bf1[4];
#pragma unroll 2
  for (int t = 0; t < NT; ++t) {
    const int buf = t & 1;
    const _Float16* aH = &sA[0][0][0] + buf * (2 * 128 * 64) + wm * (128 * 64);
    const _Float16* bH = &sB[0][0][0] + buf * (2 * 128 * 64) + bh * (128 * 64);

    PHB();
    ldA(af, aH, 0);
    ldB(bf0, bH, 0);
    if (t + 1 < NT) stageA(buf ^ 1, 0, t + 1);
    __builtin_amdgcn_s_setprio(1);
    mmaq(0, 0, af, bf0);
    __builtin_amdgcn_s_setprio(0);

    PHB();
    ldB(bf1, bH, 1);
    if (t + 1 < NT) stageA(buf ^ 1, 1, t + 1);
    __builtin_amdgcn_s_setprio(1);
    mmaq(0, 1, af, bf1);
    __builtin_amdgcn_s_setprio(0);

    PHB();
    ldA(af, aH, 1);
    if (t + 2 < NT) stageB(buf, 0, t + 2);
    __builtin_amdgcn_s_setprio(1);
    mmaq(1, 1, af, bf1);
    __builtin_amdgcn_s_setprio(0);

    PHB();
    if (t + 2 < NT) stageB(buf, 1, t + 2);
    if (t == NT - 2)
      asm volatile("s_waitcnt vmcnt(0)" ::: "memory");  // final drain
    else if (t < NT - 2)
      asm volatile("s_waitcnt vmcnt(4)" ::: "memory");  // counted, never 0
    __builtin_amdgcn_s_setprio(1);
    mmaq(1, 0, af, bf0);
    __builtin_amdgcn_s_setprio(0);
  }

  // scatter epilogue: C row = quad*4+reg, col = l16 within fragment [m89-verified]
#pragma unroll
  for (int ridx = 0; ridx < 8; ++ridx) {
#pragma unroll
    for (int cidx = 0; cidx < 4; ++cidx) {
      const int col = n0 + wn * 64 + cidx * 16 + l16;
      const float bv = bias[col];
      const int rowb = m0 + wm * 128 + ridx * 16 + quad * 4;
      const int which = col / 1280;
      const int rem = col - which * 1280;
      const int h = rem / 80;
      const int kk = rem - h * 80;
#pragma unroll
      for (int r = 0; r < 4; ++r) {
        const float v = acc[ridx][cidx][r] + bv;
        const int mrow = rowb + r;
        const int s = mrow >> 9, l = mrow & 511;
        const int shh = s * 16 + h;
        if (which == 0)
          Qf[((size_t)shh * 512 + l) * 96 + kk] = (_Float16)v;
        else if (which == 1)
          Kf[((size_t)shh * 512 + l) * 96 + kk] = (_Float16)v;
        else
          VTf[((size_t)shh * 80 + kk) * 512 + l] = (_Float16)v;
      }
    }
  }
}

// ---------------- GEMM1 (proj): 256x128 tile, BK=64, pipelined (R4 structure) --
// Out fp32(8192x1280) = attnA(8192x1280) * projT^T + bias
// Port of the verified gemm256 R4 K-loop: 4 waves (2M x 2N), per-wave 128x64
// (identical fragment/swizzle/mmaq code), one barrier per phase, counted
// vmcnt(4) checkpoint at q3. LDS = A 2x32KB + B 2x16KB = 96 KB. Grid 32x10.
// DMA per tile: A(t+1) h0 @q0 (4), A(t+1) h1 @q1 (4), B(t+2) @q2 (4);
// vmcnt(4) at q3 leaves B(t+2) in flight, drains A(t+1)+B(t+1).
__global__ __launch_bounds__(256) void gemm_k(const _Float16* __restrict__ A,
                                              const _Float16* __restrict__ BT,
                                              const float* __restrict__ bias,
                                              float* __restrict__ Out) {
  __shared__ _Float16 sA[2][2][128 * 64];  // 64 KB
  __shared__ _Float16 sB[2][2][64 * 64];   // 32 KB
  const int tid = threadIdx.x;
  const int wave = tid >> 6, lane = tid & 63;
  const int quad = lane >> 4, l16 = lane & 15;
  const int wm = wave >> 1, wn = wave & 1;  // wave grid 2M x 2N, per-wave 128x64
  const int KD = 1280, NT = 20;

  const int m0 = blockIdx.x * 256;
  const int n0 = blockIdx.y * 128;

  f32x4 acc[8][4] = {};

  // stage one A half-tile (128x64 = 16 KB) in 4 rounds of 256 thr x 16 B
  auto stageA = [&](int buf, int half, int kt) {
#pragma unroll
    for (int c = 0; c < 4; ++c) {
      const int s = c * 256 + tid;
      const int row = s >> 3;
      const int lg = (s & 7) ^ (row & 7);
      async16(A + (size_t)(m0 + half * 128 + row) * KD + kt * 64 + lg * 8,
              &sA[buf][half][(size_t)(c * 256 + wave * 64) * 8]);
    }
  };
  // stage the full B tile (128x64 = 16 KB) in 4 rounds (both col-halves, contiguous)
  auto stageB = [&](int buf, int kt) {
#pragma unroll
    for (int c = 0; c < 4; ++c) {
      const int s = c * 256 + tid;
      const int row = s >> 3;  // 0..127 spans both halves of sB[buf]
      const int lg = (s & 7) ^ (row & 7);
      async16(BT + (size_t)(n0 + row) * KD + kt * 64 + lg * 8,
              &sB[buf][0][(size_t)(c * 256 + wave * 64) * 8]);
    }
  };
  auto ldA = [&](half8* af, const _Float16* hp, int rh) {
#pragma unroll
    for (int i = 0; i < 4; ++i)
#pragma unroll
      for (int kk = 0; kk < 2; ++kk) {
        const int lrow = rh * 64 + i * 16 + l16;
        const int pg = (kk * 4 + quad) ^ (l16 & 7);
        af[i * 2 + kk] = *(const half8*)(hp + lrow * 64 + pg * 8);
      }
  };
  auto ldB = [&](half8* bf, const _Float16* hp, int ch) {
#pragma unroll
    for (int j = 0; j < 2; ++j)
#pragma unroll
      for (int kk = 0; kk < 2; ++kk) {
        const int brow = ch * 32 + j * 16 + l16;   // within this wave's 64-row half
        const int pg = (kk * 4 + quad) ^ (l16 & 7);
        bf[j * 2 + kk] = *(const half8*)(hp + brow * 64 + pg * 8);
      }
  };
  auto mmaq = [&](int r, int c, const half8* af, const half8* bf) {
#pragma unroll
    for (int i = 0; i < 4; ++i)
#pragma unroll
      for (int j = 0; j < 2; ++j)
#pragma unroll
        for (int kk = 0; kk < 2; ++kk)
          acc[r * 4 + i][c * 2 + j] =
              MFMA(af[i * 2 + kk], bf[j * 2 + kk], acc[r * 4 + i][c * 2 + j]);
  };

  // prologue: A(0) both halves, B(0), B(1); vmcnt(4) leaves B(1) in flight
  stageA(0, 0, 0); stageA(0, 1, 0);
  stageB(0, 0);
  stageB(1, 1);
  asm volatile("s_waitcnt vmcnt(4)" ::: "memory");

  half8 af[8], bf0[4], bf1[4];
#pragma unroll 2
  for (int t = 0; t < NT; ++t) {
    const int buf = t & 1;
    const _Float16* aH = &sA[0][0][0] + buf * (2 * 128 * 64) + wm * (128 * 64);
    const _Float16* bH = &sB[0][0][0] + buf * (2 * 64 * 64) + wn * (64 * 64);

    PHB();
    ldA(af, aH, 0);
    ldB(bf0, bH, 0);
    if (t + 1 < NT) stageA(buf ^ 1, 0, t + 1);
    __builtin_amdgcn_s_setprio(1);
    mmaq(0, 0, af, bf0);
    __builtin_amdgcn_s_setprio(0);

    PHB();
    ldB(bf1, bH, 1);
    if (t + 1 < NT) stageA(buf ^ 1, 1, t + 1);
    __builtin_amdgcn_s_setprio(1);
    mmaq(0, 1, af, bf1);
    __builtin_amdgcn_s_setprio(0);

    PHB();
    ldA(af, aH, 1);
    if (t + 2 < NT) stageB(buf, t + 2);
    __builtin_amdgcn_s_setprio(1);
    mmaq(1, 1, af, bf1);
    __builtin_amdgcn_s_setprio(0);

    PHB();
    if (t == NT - 2)
      asm volatile("s_waitcnt vmcnt(0)" ::: "memory");  // final drain
    else if (t < NT - 2)
      asm volatile("s_waitcnt vmcnt(4)" ::: "memory");  // counted, never 0
    __builtin_amdgcn_s_setprio(1);
    mmaq(1, 0, af, bf0);
    __builtin_amdgcn_s_setprio(0);
  }

  // epilogue: linear fp32 store + bias
#pragma unroll
  for (int ridx = 0; ridx < 8; ++ridx) {
#pragma unroll
    for (int cidx = 0; cidx < 4; ++cidx) {
      const int col = n0 + wn * 64 + cidx * 16 + l16;
      const float bv = bias[col];
      const int rowb = m0 + wm * 128 + ridx * 16 + quad * 4;
#pragma unroll
      for (int r = 0; r < 4; ++r)
        Out[(size_t)(rowb + r) * 1280 + col] = acc[ridx][cidx][r] + bv;
    }
  }
}

// ---------------- RoPE in-place on Qf/Kf + zero the k-pad [80,96), vectorized --
// 10 threads per row; each handles 4 rotation pairs via half4/float4 loads
// (8-16 B accesses vs old scalar 2-4 B; 2.6M threads vs old 16.7M).
__global__ __launch_bounds__(256) void rope_k(_Float16* __restrict__ Qf,
                                              _Float16* __restrict__ Kf,
                                              const float* __restrict__ cosNK,
                                              const float* __restrict__ sinNK) {
  const int gid = blockIdx.x * 256 + threadIdx.x;  // 2,621,440 = 262144 rows * 10
  const int jt = gid % 10;
  const int row = gid / 10;
  const int qk = row >> 17;
  const int r = row & 131071;      // (s*16+h)*512 + l
  _Float16* buf = qk ? Kf : Qf;
  const int l = r & 511;
  const int s = r >> 13;
  const int t = s * 512 + l;
  const size_t base = (size_t)r * 96;
  const int j0 = jt * 4;

  half4v v1 = *(const half4v*)(buf + base + j0);
  half4v v2 = *(const half4v*)(buf + base + 40 + j0);
  f32x4 c1 = *(const f32x4*)(cosNK + (size_t)t * 80 + j0);
  f32x4 s1 = *(const f32x4*)(sinNK + (size_t)t * 80 + j0);
  f32x4 c2 = *(const f32x4*)(cosNK + (size_t)t * 80 + 40 + j0);
  f32x4 s2 = *(const f32x4*)(sinNK + (size_t)t * 80 + 40 + j0);
  half4v o1, o2;
#pragma unroll
  for (int e = 0; e < 4; ++e) {
    const float a = (float)v1[e], b = (float)v2[e];
    o1[e] = (_Float16)(a * c1[e] - b * s1[e]);
    o2[e] = (_Float16)(b * c2[e] + a * s2[e]);
  }
  *(half4v*)(buf + base + j0) = o1;
  *(half4v*)(buf + base + 40 + j0) = o2;
  if (jt < 2) {  // zero pad kk = 80..95 (two half8 stores)
    half8 z = {};
    *(half8*)(buf + base + 80 + jt * 8) = z;
  }
}

// ---------------- flash attention (S^T form, no-max softmax, sum via ones) ----
__global__ __launch_bounds__(256) void attn_k(const _Float16* __restrict__ Qf,
                                              const _Float16* __restrict__ Kf,
                                              const _Float16* __restrict__ VTf,
                                              _Float16* __restrict__ attnA) {
  __shared__ _Float16 sP[128 * 72];   // P tile, row stride 72
  __shared__ _Float16 sK[64 * 104];   // K tile, row stride 104 (conflict-free)
  __shared__ _Float16 sV[96 * 72];    // rows 0..79: V^T tile; rows 80..95: ones
  const int tid = threadIdx.x;
  const int wave = tid >> 6, lane = tid & 63;
  const int quad = lane >> 4, l16 = lane & 15;
  const int shh = blockIdx.x;  // s*16+h
  const int qt = blockIdx.y;   // 0..3
  const int h = shh & 15;
  const int s = shh >> 4;

  const _Float16* Qb = Qf + ((size_t)shh * 512 + qt * 128) * 96;
  const _Float16* Kb0 = Kf + (size_t)shh * 512 * 96;
  const _Float16* Vb0 = VTf + (size_t)shh * 80 * 512;

  // Q fragments straight from global (rows are lane-exact), pre-scaled
  const _Float16 c1h = (_Float16)(ATT_SCALE * LOG2E);
  half8 qf[2][3];
#pragma unroll
  for (int rt = 0; rt < 2; ++rt)
#pragma unroll
    for (int ks = 0; ks < 3; ++ks) {
      half8 t = *(const half8*)(Qb + (size_t)(wave * 32 + rt * 16 + l16) * 96 +
                                ks * 32 + quad * 8);
#pragma unroll
      for (int e = 0; e < 8; ++e) t[e] *= c1h;
      qf[rt][ks] = t;
    }

  // ones rows for the row-sum trick
  for (int idx = tid; idx < 16 * 72; idx += 256) sV[80 * 72 + idx] = (_Float16)1.f;

  f32x4 o[2][6] = {};  // ft 0..4: output features; ft 5: row sum

  for (int kc = 0; kc < 8; ++kc) {
    __syncthreads();  // prev iter LDS reads done (iter0: ones visible)
    // K tile -> sK, padded stride 104 halves (208 B), masked DMA (13 chunks)
    const _Float16* Kb = Kb0 + (size_t)kc * 64 * 96;
#pragma unroll
    for (int c = 0; c < 4; ++c) {
      const int j = wave + 4 * c;
      if (j < 13) {
        const int off = j * 1024 + lane * 16;  // LDS byte offset
        const int krow = off / 208;
        const int kcol = off - krow * 208;     // bytes within padded row
        if (kcol < 192)
          async16(Kb + (size_t)krow * 96 + (kcol >> 1), &sK[j * 512]);
      }
    }
    // V^T tile -> sV, padded stride 72 halves (144 B), masked DMA (12 chunks)
#pragma unroll
    for (int c = 0; c < 3; ++c) {
      const int j = wave + 4 * c;
      const int off = j * 1024 + lane * 16;
      const int vrow = off / 144;
      const int colb = off - vrow * 144;
      if (vrow < 80 && colb < 128)
        async16(Vb0 + (size_t)vrow * 512 + kc * 64 + (colb >> 1), &sV[j * 512]);
    }
    __syncthreads();

    // S^T = K Q^T (operand swap): lane holds S[q=l16][k=mt*16+quad*4+r]
    f32x4 sacc[2][4] = {};  // [rt][mt]
#pragma unroll
    for (int mt = 0; mt < 4; ++mt) {
#pragma unroll
      for (int ks = 0; ks < 3; ++ks) {
        half8 kb = *(const half8*)&sK[(mt * 16 + l16) * 104 + ks * 32 + quad * 8];
        sacc[0][mt] = MFMA(kb, qf[0][ks], sacc[0][mt]);
        sacc[1][mt] = MFMA(kb, qf[1][ks], sacc[1][mt]);
      }
    }

    // p = exp2(s), packed pairs (consecutive k!), one b64 store per (rt,mt)
#pragma unroll
    for (int rt = 0; rt < 2; ++rt) {
#pragma unroll
      for (int mt = 0; mt < 4; ++mt) {
        union { fp16x2 h2[2]; half4v h4; } u;
        u.h2[0] = __builtin_amdgcn_cvt_pkrtz(
            __builtin_amdgcn_exp2f(sacc[rt][mt][0]),
            __builtin_amdgcn_exp2f(sacc[rt][mt][1]));
        u.h2[1] = __builtin_amdgcn_cvt_pkrtz(
            __builtin_amdgcn_exp2f(sacc[rt][mt][2]),
            __builtin_amdgcn_exp2f(sacc[rt][mt][3]));
        *(half4v*)&sP[(wave * 32 + rt * 16 + l16) * 72 + mt * 16 + quad * 4] = u.h4;
      }
    }
    // sP rows are wave-private: per-wave LDS ordering suffices, no barrier

    // O += P V  (ft=5 accumulates the row sum via the ones rows)
#pragma unroll
    for (int ks = 0; ks < 2; ++ks) {
      half8 pa[2];
      pa[0] = *(const half8*)&sP[(wave * 32 + 0 + l16) * 72 + ks * 32 + quad * 8];
      pa[1] = *(const half8*)&sP[(wave * 32 + 16 + l16) * 72 + ks * 32 + quad * 8];
#pragma unroll
      for (int ft = 0; ft < 6; ++ft) {
        half8 vb = *(const half8*)&sV[(ft * 16 + l16) * 72 + ks * 32 + quad * 8];
        o[0][ft] = MFMA(pa[0], vb, o[0][ft]);
        o[1][ft] = MFMA(pa[1], vb, o[1][ft]);
      }
    }
  }

  // epilogue: divide by row sum, store fp16 into attnA [token][h*80+f]
#pragma unroll
  for (int rt = 0; rt < 2; ++rt) {
#pragma unroll
    for (int r = 0; r < 4; ++r) {
      const float inv = 1.0f / o[rt][5][r];
      const int token = s * 512 + qt * 128 + wave * 32 + rt * 16 + quad * 4 + r;
#pragma unroll
      for (int ft = 0; ft < 5; ++ft)
        attnA[(size_t)token * 1280 + h * 80 + ft * 16 + l16] =
            (_Float16)(o[rt][ft][r] * inv);
    }
  }
}

extern "C" void kernel_launch(void* const* d_in, const int* in_sizes, int n_in,
                              void* d_out, int out_size, void* d_ws, size_t ws_size,
                              hipStream_t stream) {
  (void)in_sizes; (void)n_in; (void)out_size; (void)ws_size;
  const float* hidden = (const float*)d_in[0];
  const float* cosNK = (const float*)d_in[2];
  const float* sinNK = (const float*)d_in[3];
  const float* qkv_w = (const float*)d_in[4];
  const float* qkv_b = (const float*)d_in[5];
  const float* proj_w = (const float*)d_in[6];
  const float* proj_b = (const float*)d_in[7];
  float* out = (float*)d_out;

  char* ws = (char*)d_ws;
  _Float16* hA    = (_Float16*)(ws);                   // 8192x1280        20971520 B
  _Float16* wT    = (_Float16*)(ws + 20971520);        // 3840x1280         9830400 B
  _Float16* projT = (_Float16*)(ws + 30801920);        // 1280x1280         3276800 B
  _Float16* Qf    = (_Float16*)(ws + 34078720);        // 256x512x96       25165824 B
  _Float16* Kf    = (_Float16*)(ws + 59244544);        // 256x512x96       25165824 B
  _Float16* VTf   = (_Float16*)(ws + 84410368);        // 256x80x512       20971520 B
  _Float16* attnA = (_Float16*)(ws + 105381888);       // 8192x1280        20971520 B

  cvt_k<<<10240, 256, 0, stream>>>(hidden, hA, 2621440);
  transpose_cvt_k<<<dim3(120, 40), 256, 0, stream>>>(qkv_w, wT, 1280, 3840);
  transpose_cvt_k<<<dim3(40, 40), 256, 0, stream>>>(proj_w, projT, 1280, 1280);
  gemm256_k<<<480, 512, 0, stream>>>(hA, wT, qkv_b, Qf, Kf, VTf);
  rope_k<<<10240, 256, 0, stream>>>(Qf, Kf, cosNK, sinNK);
  attn_k<<<dim3(256, 4), 256, 0, stream>>>(Qf, Kf, VTf, attnA);
  gemm_k<<<dim3(32, 10), 256, 0, stream>>>(attnA, projT, proj_b, out);
}

// Round 7
// 339.340 us; speedup vs baseline: 1.0696x; 1.0573x over previous
//
#include <hip/hip_runtime.h>

// Problem constants (fixed shape)
// N=8192 tokens, D=1280, H=16 heads, K=80 head dim (pad 96), S=16 segs, L=512
#define LOG2E 1.44269504088896340736f
#define ATT_SCALE 0.11180339887498949f  // 80^-0.5

typedef _Float16 half8 __attribute__((ext_vector_type(8)));
typedef _Float16 half4v __attribute__((ext_vector_type(4)));
typedef __fp16 fp16x2 __attribute__((ext_vector_type(2)));
typedef float f32x4 __attribute__((ext_vector_type(4)));

#define MFMA(a, b, c) __builtin_amdgcn_mfma_f32_16x16x32_f16((a), (b), (c), 0, 0, 0)

__device__ __forceinline__ void async16(const _Float16* g, _Float16* l) {
  __builtin_amdgcn_global_load_lds(
      (const __attribute__((address_space(1))) unsigned int*)g,
      (__attribute__((address_space(3))) unsigned int*)l,
      16, 0, 0);
}

#define FENCE() asm volatile("" ::: "memory")
// one barrier per phase, memory fence only (no sched pins — m141)
#define PHB()                                   \
  do {                                          \
    FENCE();                                    \
    __builtin_amdgcn_s_barrier();               \
    FENCE();                                    \
  } while (0)

// ---------------- fp32 -> fp16 convert (hidden) ----------------
__global__ __launch_bounds__(256) void cvt_k(const float* __restrict__ in,
                                             _Float16* __restrict__ out, int n4) {
  int i = blockIdx.x * 256 + threadIdx.x;
  if (i < n4) {
    f32x4 v = ((const f32x4*)in)[i];
    half4v hv;
    hv[0] = (_Float16)v[0]; hv[1] = (_Float16)v[1];
    hv[2] = (_Float16)v[2]; hv[3] = (_Float16)v[3];
    ((half4v*)out)[i] = hv;
  }
}

// ---------------- transpose + convert: in R x C fp32 -> out C x R fp16 ----------
__global__ __launch_bounds__(256) void transpose_cvt_k(const float* __restrict__ in,
                                                       _Float16* __restrict__ out,
                                                       int R, int C) {
  __shared__ float tile[32][33];
  const int tx = threadIdx.x & 31, ty = threadIdx.x >> 5;
  const int c0 = blockIdx.x * 32, r0 = blockIdx.y * 32;
#pragma unroll
  for (int i = 0; i < 32; i += 8)
    tile[ty + i][tx] = in[(size_t)(r0 + ty + i) * C + c0 + tx];
  __syncthreads();
#pragma unroll
  for (int i = 0; i < 32; i += 8)
    out[(size_t)(c0 + ty + i) * R + r0 + tx] = (_Float16)tile[tx][ty + i];
}

// ---------------- GEMM0: 256x256 tile, BK=64, 4-phase K-loop (R4, proven) ----
// C = A(8192x1280) * BT^T (3840x1280), scatter epilogue -> Qf/Kf/VTf
// R4 verbatim: 115 us, MfmaUtil 29%, conflicts 0, FETCH 59 MB (ideal).
// Held as control this round.
__global__ __launch_bounds__(512, 2) void gemm256_k(const _Float16* __restrict__ A,
                                                    const _Float16* __restrict__ BT,
                                                    const float* __restrict__ bias,
                                                    _Float16* __restrict__ Qf,
                                                    _Float16* __restrict__ Kf,
                                                    _Float16* __restrict__ VTf) {
  __shared__ _Float16 sA[2][2][128 * 64];  // [buf][half][row*64 + col], 64 KB
  __shared__ _Float16 sB[2][2][128 * 64];  // 64 KB
  const int tid = threadIdx.x;
  const int wave = tid >> 6, lane = tid & 63;
  const int quad = lane >> 4, l16 = lane & 15;
  const int wm = wave >> 2, wn = wave & 3;      // wave grid 2M x 4N
  const int bh = wn >> 1, brb = (wn & 1) * 64;  // B half + row base within half
  const int KD = 1280, NT = 20;                 // 20 K-tiles of 64

  // A-pinned XCD mapping: XCD x owns tm in [4x,4x+4), sweeps tn
  const int id = blockIdx.x;
  const int xcd = id & 7;
  const int qq = (id >> 3) & 3;
  const int tn = id >> 5;           // 0..14
  const int tm = xcd * 4 + qq;      // 0..31
  const int m0 = tm * 256, n0 = tn * 256;

  f32x4 acc[8][4] = {};

  auto stageA = [&](int buf, int half, int kt) {
#pragma unroll
    for (int c = 0; c < 2; ++c) {
      const int s = c * 512 + wave * 64 + lane;
      const int row = s >> 3;
      const int lg = (s & 7) ^ (row & 7);
      async16(A + (size_t)(m0 + half * 128 + row) * KD + kt * 64 + lg * 8,
              &sA[buf][half][(size_t)(c * 512 + wave * 64) * 8]);
    }
  };
  auto stageB = [&](int buf, int half, int kt) {
#pragma unroll
    for (int c = 0; c < 2; ++c) {
      const int s = c * 512 + wave * 64 + lane;
      const int row = s >> 3;
      const int lg = (s & 7) ^ (row & 7);
      async16(BT + (size_t)(n0 + half * 128 + row) * KD + kt * 64 + lg * 8,
              &sB[buf][half][(size_t)(c * 512 + wave * 64) * 8]);
    }
  };
  auto ldA = [&](half8* af, const _Float16* hp, int rh) {
#pragma unroll
    for (int i = 0; i < 4; ++i)
#pragma unroll
      for (int kk = 0; kk < 2; ++kk) {
        const int lrow = rh * 64 + i * 16 + l16;
        const int pg = (kk * 4 + quad) ^ (l16 & 7);
        af[i * 2 + kk] = *(const half8*)(hp + lrow * 64 + pg * 8);
      }
  };
  auto ldB = [&](half8* bf, const _Float16* hp, int ch) {
#pragma unroll
    for (int j = 0; j < 2; ++j)
#pragma unroll
      for (int kk = 0; kk < 2; ++kk) {
        const int brow = brb + ch * 32 + j * 16 + l16;
        const int pg = (kk * 4 + quad) ^ (l16 & 7);
        bf[j * 2 + kk] = *(const half8*)(hp + brow * 64 + pg * 8);
      }
  };
  auto mmaq = [&](int r, int c, const half8* af, const half8* bf) {
#pragma unroll
    for (int i = 0; i < 4; ++i)
#pragma unroll
      for (int j = 0; j < 2; ++j)
#pragma unroll
        for (int kk = 0; kk < 2; ++kk)
          acc[r * 4 + i][c * 2 + j] =
              MFMA(af[i * 2 + kk], bf[j * 2 + kk], acc[r * 4 + i][c * 2 + j]);
  };

  stageA(0, 0, 0); stageA(0, 1, 0);
  stageB(0, 0, 0); stageB(0, 1, 0);
  stageB(1, 0, 1); stageB(1, 1, 1);
  asm volatile("s_waitcnt vmcnt(4)" ::: "memory");

  half8 af[8], bf0[4], bf1[4];
#pragma unroll 2
  for (int t = 0; t < NT; ++t) {
    const int buf = t & 1;
    const _Float16* aH = &sA[0][0][0] + buf * (2 * 128 * 64) + wm * (128 * 64);
    const _Float16* bH = &sB[0][0][0] + buf * (2 * 128 * 64) + bh * (128 * 64);

    PHB();
    ldA(af, aH, 0);
    ldB(bf0, bH, 0);
    if (t + 1 < NT) stageA(buf ^ 1, 0, t + 1);
    __builtin_amdgcn_s_setprio(1);
    mmaq(0, 0, af, bf0);
    __builtin_amdgcn_s_setprio(0);

    PHB();
    ldB(bf1, bH, 1);
    if (t + 1 < NT) stageA(buf ^ 1, 1, t + 1);
    __builtin_amdgcn_s_setprio(1);
    mmaq(0, 1, af, bf1);
    __builtin_amdgcn_s_setprio(0);

    PHB();
    ldA(af, aH, 1);
    if (t + 2 < NT) stageB(buf, 0, t + 2);
    __builtin_amdgcn_s_setprio(1);
    mmaq(1, 1, af, bf1);
    __builtin_amdgcn_s_setprio(0);

    PHB();
    if (t + 2 < NT) stageB(buf, 1, t + 2);
    if (t == NT - 2)
      asm volatile("s_waitcnt vmcnt(0)" ::: "memory");  // final drain
    else if (t < NT - 2)
      asm volatile("s_waitcnt vmcnt(4)" ::: "memory");  // counted, never 0
    __builtin_amdgcn_s_setprio(1);
    mmaq(1, 0, af, bf0);
    __builtin_amdgcn_s_setprio(0);
  }

  // scatter epilogue: C row = quad*4+reg, col = l16 within fragment [m89-verified]
#pragma unroll
  for (int ridx = 0; ridx < 8; ++ridx) {
#pragma unroll
    for (int cidx = 0; cidx < 4; ++cidx) {
      const int col = n0 + wn * 64 + cidx * 16 + l16;
      const float bv = bias[col];
      const int rowb = m0 + wm * 128 + ridx * 16 + quad * 4;
      const int which = col / 1280;
      const int rem = col - which * 1280;
      const int h = rem / 80;
      const int kk = rem - h * 80;
#pragma unroll
      for (int r = 0; r < 4; ++r) {
        const float v = acc[ridx][cidx][r] + bv;
        const int mrow = rowb + r;
        const int s = mrow >> 9, l = mrow & 511;
        const int shh = s * 16 + h;
        if (which == 0)
          Qf[((size_t)shh * 512 + l) * 96 + kk] = (_Float16)v;
        else if (which == 1)
          Kf[((size_t)shh * 512 + l) * 96 + kk] = (_Float16)v;
        else
          VTf[((size_t)shh * 80 + kk) * 512 + l] = (_Float16)v;
      }
    }
  }
}

// ---------------- GEMM1 (proj): 128x128 tile, BK=64, 2-phase, 2 blocks/CU -----
// Out fp32(8192x1280) = attnA(8192x1280) * projT^T + bias
//
// Round-7 redesign. R6's 256x128/96KB version was 1 block/CU x 4 waves =
// 1 wave/SIMD (occupancy-starved -> regressed). Now: 4 waves, per-wave 64x64
// (acc[4][4] = 64 AGPR; ~160 regs total -> 3 waves/SIMD allowed), LDS
// 2buf x (A 16KB + B 16KB) = 64 KB -> TWO independent blocks/CU = 8 waves/CU
// with uncorrelated barrier groups: block A's vmcnt(0)/barrier stall is
// covered by block B's MFMA (m114; catalog's 2-phase minimum, m230: 92% of
// 8-phase). K-loop per tile: stage(t+1)->buf^1 FIRST (latency head start),
// ds_read 16 b128 + 32 MFMA on buf, vmcnt(0)+barrier once. Race audit:
// buf^1's last reads were tile t-1 (barrier-separated); reads of buf see
// tile t-1's drain (vmcnt(0) before barrier, all waves).
// Locality: grid (64,10) -> all 10 blocks sharing an A panel land on one
// XCD (id%8 = x%8); B (3.3 MB) L2-fits per XCD. R4's proven 128B-row
// swizzle reused verbatim (conflicts 0).
__global__ __launch_bounds__(256) void gemm_k(const _Float16* __restrict__ A,
                                              const _Float16* __restrict__ BT,
                                              const float* __restrict__ bias,
                                              float* __restrict__ Out) {
  __shared__ _Float16 sA[2][128 * 64];  // 32 KB
  __shared__ _Float16 sB[2][128 * 64];  // 32 KB
  const int tid = threadIdx.x;
  const int wave = tid >> 6, lane = tid & 63;
  const int quad = lane >> 4, l16 = lane & 15;
  const int wm = wave >> 1, wn = wave & 1;  // wave grid 2M x 2N, per-wave 64x64
  const int KD = 1280, NT = 20;

  const int m0 = blockIdx.x * 128;
  const int n0 = blockIdx.y * 128;

  f32x4 acc[4][4] = {};

  // stage a full 128x64 operand tile (16 KB) in 4 rounds of 256 thr x 16 B
  auto stage = [&](_Float16* dst, const _Float16* src, int rbase, int kt) {
#pragma unroll
    for (int c = 0; c < 4; ++c) {
      const int s = c * 256 + tid;
      const int row = s >> 3;
      const int lg = (s & 7) ^ (row & 7);
      async16(src + (size_t)(rbase + row) * KD + kt * 64 + lg * 8,
              dst + (size_t)(c * 256 + wave * 64) * 8);
    }
  };
  // A fragments: 4 row-frags x 2 ksteps from this wave's 64-row half
  auto ldA = [&](half8* af, const _Float16* hp) {
#pragma unroll
    for (int i = 0; i < 4; ++i)
#pragma unroll
      for (int kk = 0; kk < 2; ++kk) {
        const int lrow = wm * 64 + i * 16 + l16;
        const int pg = (kk * 4 + quad) ^ (l16 & 7);
        af[i * 2 + kk] = *(const half8*)(hp + lrow * 64 + pg * 8);
      }
  };
  auto ldB = [&](half8* bf, const _Float16* hp) {
#pragma unroll
    for (int j = 0; j < 4; ++j)
#pragma unroll
      for (int kk = 0; kk < 2; ++kk) {
        const int brow = wn * 64 + j * 16 + l16;
        const int pg = (kk * 4 + quad) ^ (l16 & 7);
        bf[j * 2 + kk] = *(const half8*)(hp + brow * 64 + pg * 8);
      }
  };

  // prologue: tile0 into buf0, full drain
  stage(&sA[0][0], A, m0, 0);
  stage(&sB[0][0], BT, n0, 0);
  asm volatile("s_waitcnt vmcnt(0)" ::: "memory");
  PHB();

  half8 af[8], bf[8];
#pragma unroll 2
  for (int t = 0; t < NT; ++t) {
    const int buf = t & 1;
    // issue next tile's DMA first: latency hides under this tile's reads+MFMA
    if (t + 1 < NT) {
      stage(&sA[buf ^ 1][0], A, m0, t + 1);
      stage(&sB[buf ^ 1][0], BT, n0, t + 1);
    }
    ldA(af, &sA[buf][0]);
    ldB(bf, &sB[buf][0]);
    __builtin_amdgcn_s_setprio(1);
#pragma unroll
    for (int i = 0; i < 4; ++i)
#pragma unroll
      for (int j = 0; j < 4; ++j)
#pragma unroll
        for (int kk = 0; kk < 2; ++kk)
          acc[i][j] = MFMA(af[i * 2 + kk], bf[j * 2 + kk], acc[i][j]);
    __builtin_amdgcn_s_setprio(0);
    if (t + 1 < NT)
      asm volatile("s_waitcnt vmcnt(0)" ::: "memory");  // next tile landed
    PHB();
  }

  // epilogue: linear fp32 store + bias
#pragma unroll
  for (int i = 0; i < 4; ++i) {
#pragma unroll
    for (int j = 0; j < 4; ++j) {
      const int col = n0 + wn * 64 + j * 16 + l16;
      const float bv = bias[col];
      const int rowb = m0 + wm * 64 + i * 16 + quad * 4;
#pragma unroll
      for (int r = 0; r < 4; ++r)
        Out[(size_t)(rowb + r) * 1280 + col] = acc[i][j][r] + bv;
    }
  }
}

// ---------------- RoPE in-place on Qf/Kf + zero the k-pad [80,96), vectorized --
// 10 threads per row; each handles 4 rotation pairs via half4/float4 loads
// (8-16 B accesses vs old scalar 2-4 B; 2.6M threads vs old 16.7M).
__global__ __launch_bounds__(256) void rope_k(_Float16* __restrict__ Qf,
                                              _Float16* __restrict__ Kf,
                                              const float* __restrict__ cosNK,
                                              const float* __restrict__ sinNK) {
  const int gid = blockIdx.x * 256 + threadIdx.x;  // 2,621,440 = 262144 rows * 10
  const int jt = gid % 10;
  const int row = gid / 10;
  const int qk = row >> 17;
  const int r = row & 131071;      // (s*16+h)*512 + l
  _Float16* buf = qk ? Kf : Qf;
  const int l = r & 511;
  const int s = r >> 13;
  const int t = s * 512 + l;
  const size_t base = (size_t)r * 96;
  const int j0 = jt * 4;

  half4v v1 = *(const half4v*)(buf + base + j0);
  half4v v2 = *(const half4v*)(buf + base + 40 + j0);
  f32x4 c1 = *(const f32x4*)(cosNK + (size_t)t * 80 + j0);
  f32x4 s1 = *(const f32x4*)(sinNK + (size_t)t * 80 + j0);
  f32x4 c2 = *(const f32x4*)(cosNK + (size_t)t * 80 + 40 + j0);
  f32x4 s2 = *(const f32x4*)(sinNK + (size_t)t * 80 + 40 + j0);
  half4v o1, o2;
#pragma unroll
  for (int e = 0; e < 4; ++e) {
    const float a = (float)v1[e], b = (float)v2[e];
    o1[e] = (_Float16)(a * c1[e] - b * s1[e]);
    o2[e] = (_Float16)(b * c2[e] + a * s2[e]);
  }
  *(half4v*)(buf + base + j0) = o1;
  *(half4v*)(buf + base + 40 + j0) = o2;
  if (jt < 2) {  // zero pad kk = 80..95 (two half8 stores)
    half8 z = {};
    *(half8*)(buf + base + 80 + jt * 8) = z;
  }
}

// ---------------- flash attention (S^T form, no-max softmax, sum via ones) ----
__global__ __launch_bounds__(256) void attn_k(const _Float16* __restrict__ Qf,
                                              const _Float16* __restrict__ Kf,
                                              const _Float16* __restrict__ VTf,
                                              _Float16* __restrict__ attnA) {
  __shared__ _Float16 sP[128 * 72];   // P tile, row stride 72
  __shared__ _Float16 sK[64 * 104];   // K tile, row stride 104 (conflict-free)
  __shared__ _Float16 sV[96 * 72];    // rows 0..79: V^T tile; rows 80..95: ones
  const int tid = threadIdx.x;
  const int wave = tid >> 6, lane = tid & 63;
  const int quad = lane >> 4, l16 = lane & 15;
  const int shh = blockIdx.x;  // s*16+h
  const int qt = blockIdx.y;   // 0..3
  const int h = shh & 15;
  const int s = shh >> 4;

  const _Float16* Qb = Qf + ((size_t)shh * 512 + qt * 128) * 96;
  const _Float16* Kb0 = Kf + (size_t)shh * 512 * 96;
  const _Float16* Vb0 = VTf + (size_t)shh * 80 * 512;

  // Q fragments straight from global (rows are lane-exact), pre-scaled
  const _Float16 c1h = (_Float16)(ATT_SCALE * LOG2E);
  half8 qf[2][3];
#pragma unroll
  for (int rt = 0; rt < 2; ++rt)
#pragma unroll
    for (int ks = 0; ks < 3; ++ks) {
      half8 t = *(const half8*)(Qb + (size_t)(wave * 32 + rt * 16 + l16) * 96 +
                                ks * 32 + quad * 8);
#pragma unroll
      for (int e = 0; e < 8; ++e) t[e] *= c1h;
      qf[rt][ks] = t;
    }

  // ones rows for the row-sum trick
  for (int idx = tid; idx < 16 * 72; idx += 256) sV[80 * 72 + idx] = (_Float16)1.f;

  f32x4 o[2][6] = {};  // ft 0..4: output features; ft 5: row sum

  for (int kc = 0; kc < 8; ++kc) {
    __syncthreads();  // prev iter LDS reads done (iter0: ones visible)
    // K tile -> sK, padded stride 104 halves (208 B), masked DMA (13 chunks)
    const _Float16* Kb = Kb0 + (size_t)kc * 64 * 96;
#pragma unroll
    for (int c = 0; c < 4; ++c) {
      const int j = wave + 4 * c;
      if (j < 13) {
        const int off = j * 1024 + lane * 16;  // LDS byte offset
        const int krow = off / 208;
        const int kcol = off - krow * 208;     // bytes within padded row
        if (kcol < 192)
          async16(Kb + (size_t)krow * 96 + (kcol >> 1), &sK[j * 512]);
      }
    }
    // V^T tile -> sV, padded stride 72 halves (144 B), masked DMA (12 chunks)
#pragma unroll
    for (int c = 0; c < 3; ++c) {
      const int j = wave + 4 * c;
      const int off = j * 1024 + lane * 16;
      const int vrow = off / 144;
      const int colb = off - vrow * 144;
      if (vrow < 80 && colb < 128)
        async16(Vb0 + (size_t)vrow * 512 + kc * 64 + (colb >> 1), &sV[j * 512]);
    }
    __syncthreads();

    // S^T = K Q^T (operand swap): lane holds S[q=l16][k=mt*16+quad*4+r]
    f32x4 sacc[2][4] = {};  // [rt][mt]
#pragma unroll
    for (int mt = 0; mt < 4; ++mt) {
#pragma unroll
      for (int ks = 0; ks < 3; ++ks) {
        half8 kb = *(const half8*)&sK[(mt * 16 + l16) * 104 + ks * 32 + quad * 8];
        sacc[0][mt] = MFMA(kb, qf[0][ks], sacc[0][mt]);
        sacc[1][mt] = MFMA(kb, qf[1][ks], sacc[1][mt]);
      }
    }

    // p = exp2(s), packed pairs (consecutive k!), one b64 store per (rt,mt)
#pragma unroll
    for (int rt = 0; rt < 2; ++rt) {
#pragma unroll
      for (int mt = 0; mt < 4; ++mt) {
        union { fp16x2 h2[2]; half4v h4; } u;
        u.h2[0] = __builtin_amdgcn_cvt_pkrtz(
            __builtin_amdgcn_exp2f(sacc[rt][mt][0]),
            __builtin_amdgcn_exp2f(sacc[rt][mt][1]));
        u.h2[1] = __builtin_amdgcn_cvt_pkrtz(
            __builtin_amdgcn_exp2f(sacc[rt][mt][2]),
            __builtin_amdgcn_exp2f(sacc[rt][mt][3]));
        *(half4v*)&sP[(wave * 32 + rt * 16 + l16) * 72 + mt * 16 + quad * 4] = u.h4;
      }
    }
    // sP rows are wave-private: per-wave LDS ordering suffices, no barrier

    // O += P V  (ft=5 accumulates the row sum via the ones rows)
#pragma unroll
    for (int ks = 0; ks < 2; ++ks) {
      half8 pa[2];
      pa[0] = *(const half8*)&sP[(wave * 32 + 0 + l16) * 72 + ks * 32 + quad * 8];
      pa[1] = *(const half8*)&sP[(wave * 32 + 16 + l16) * 72 + ks * 32 + quad * 8];
#pragma unroll
      for (int ft = 0; ft < 6; ++ft) {
        half8 vb = *(const half8*)&sV[(ft * 16 + l16) * 72 + ks * 32 + quad * 8];
        o[0][ft] = MFMA(pa[0], vb, o[0][ft]);
        o[1][ft] = MFMA(pa[1], vb, o[1][ft]);
      }
    }
  }

  // epilogue: divide by row sum, store fp16 into attnA [token][h*80+f]
#pragma unroll
  for (int rt = 0; rt < 2; ++rt) {
#pragma unroll
    for (int r = 0; r < 4; ++r) {
      const float inv = 1.0f / o[rt][5][r];
      const int token = s * 512 + qt * 128 + wave * 32 + rt * 16 + quad * 4 + r;
#pragma unroll
      for (int ft = 0; ft < 5; ++ft)
        attnA[(size_t)token * 1280 + h * 80 + ft * 16 + l16] =
            (_Float16)(o[rt][ft][r] * inv);
    }
  }
}

extern "C" void kernel_launch(void* const* d_in, const int* in_sizes, int n_in,
                              void* d_out, int out_size, void* d_ws, size_t ws_size,
                              hipStream_t stream) {
  (void)in_sizes; (void)n_in; (void)out_size; (void)ws_size;
  const float* hidden = (const float*)d_in[0];
  const float* cosNK = (const float*)d_in[2];
  const float* sinNK = (const float*)d_in[3];
  const float* qkv_w = (const float*)d_in[4];
  const float* qkv_b = (const float*)d_in[5];
  const float* proj_w = (const float*)d_in[6];
  const float* proj_b = (const float*)d_in[7];
  float* out = (float*)d_out;

  char* ws = (char*)d_ws;
  _Float16* hA    = (_Float16*)(ws);                   // 8192x1280        20971520 B
  _Float16* wT    = (_Float16*)(ws + 20971520);        // 3840x1280         9830400 B
  _Float16* projT = (_Float16*)(ws + 30801920);        // 1280x1280         3276800 B
  _Float16* Qf    = (_Float16*)(ws + 34078720);        // 256x512x96       25165824 B
  _Float16* Kf    = (_Float16*)(ws + 59244544);        // 256x512x96       25165824 B
  _Float16* VTf   = (_Float16*)(ws + 84410368);        // 256x80x512       20971520 B
  _Float16* attnA = (_Float16*)(ws + 105381888);       // 8192x1280        20971520 B

  cvt_k<<<10240, 256, 0, stream>>>(hidden, hA, 2621440);
  transpose_cvt_k<<<dim3(120, 40), 256, 0, stream>>>(qkv_w, wT, 1280, 3840);
  transpose_cvt_k<<<dim3(40, 40), 256, 0, stream>>>(proj_w, projT, 1280, 1280);
  gemm256_k<<<480, 512, 0, stream>>>(hA, wT, qkv_b, Qf, Kf, VTf);
  rope_k<<<10240, 256, 0, stream>>>(Qf, Kf, cosNK, sinNK);
  attn_k<<<dim3(256, 4), 256, 0, stream>>>(Qf, Kf, VTf, attnA);
  gemm_k<<<dim3(64, 10), 256, 0, stream>>>(attnA, projT, proj_b, out);
}